// Round 11
// baseline (123.906 us; speedup 1.0000x reference)
//
#include <hip/hip_runtime.h>

typedef short bf16x8 __attribute__((ext_vector_type(8)));
typedef short bf16x4 __attribute__((ext_vector_type(4)));
typedef float f32x4  __attribute__((ext_vector_type(4)));

#define NSPAN 2000
#define DSPAN 1220
#define NPAIR 65536
#define HID   150
#define HP    160          // padded hidden width
#define TW    320          // T row: [0,160) A-proj, [160,320) B-proj
#define NKS   78           // total k-steps of 32 (K = 2496 = 2 x 1248)
#define NKH   39           // k-steps per half (g half / g^2 half)
#define NMT   128          // 2048/16 row tiles
#define NNT   20           // 320/16 col tiles
#define KC    6            // k-split chunks (78 = 6*13), 13 ks each [R8-proven]
#define H1S   168          // h1 bf16 row stride (336 B, 16B aligned)
#define NCMB  189          // 9*7*3 phi combos
#define TSZ   (NSPAN * TW) // 640000 elements per T image

// prep_all grid sections
#define GA 1248            // A-fragments
#define GB 390             // Wc-fragments
#define GC 119             // combo phi table (189*160, bf16)
#define GD 13              // W2 fragments (3200)

static __device__ __forceinline__ short f2bf(float x) {
  unsigned u = __builtin_bit_cast(unsigned, x);
  u = (u + 0x7FFFu + ((u >> 16) & 1u)) >> 16;   // RNE
  return (short)u;
}
static __device__ __forceinline__ float bf2f(short s) {
  unsigned u = ((unsigned)(unsigned short)s) << 16;
  return __builtin_bit_cast(float, u);
}

// ---------------- prep_all: fragments + combo table ----------------
__global__ __launch_bounds__(256)
void prep_all(const float* __restrict__ g, const float* __restrict__ W1,
              const float* __restrict__ b1, const float* __restrict__ de,
              const float* __restrict__ ge, const float* __restrict__ se,
              const float* __restrict__ W2, short* __restrict__ A_fr,
              short* __restrict__ Wc_fr, short* __restrict__ combo,
              short* __restrict__ W2_fr) {
  int b = blockIdx.x;
  int t = threadIdx.x;
  if (b < GA) {                               // ---- A fragments ----
    int tid = b * 256 + t;                    // 1248*256 = 128*39*64 exact
    int l  = tid & 63;
    int t2 = tid >> 6;
    int ks = t2 % NKH;
    int mt = t2 / NKH;
    int m  = mt * 16 + (l & 15);
    int k0 = ks * 32 + ((l >> 4) << 3);
    float x[8];
    if (m < NSPAN && k0 + 8 <= DSPAN) {       // g rows 16B-aligned
      float4 f0 = *(const float4*)&g[m * DSPAN + k0];
      float4 f1 = *(const float4*)&g[m * DSPAN + k0 + 4];
      x[0]=f0.x; x[1]=f0.y; x[2]=f0.z; x[3]=f0.w;
      x[4]=f1.x; x[5]=f1.y; x[6]=f1.z; x[7]=f1.w;
    } else {
#pragma unroll
      for (int i = 0; i < 8; ++i) {
        int k = k0 + i;
        x[i] = (m < NSPAN && k < DSPAN) ? g[m * DSPAN + k] : 0.f;
      }
    }
    short v1[8], v2[8];
#pragma unroll
    for (int i = 0; i < 8; ++i) { v1[i] = f2bf(x[i]); v2[i] = f2bf(x[i] * x[i]); }
    size_t o1 = ((size_t)(mt * NKS + ks) * 64 + l) * 8;
    *(bf16x8*)(A_fr + o1) = *(const bf16x8*)v1;
    *(bf16x8*)(A_fr + o1 + (size_t)NKH * 512) = *(const bf16x8*)v2;
  } else if (b < GA + GB) {                   // ---- Wc fragments ----
    int tid = (b - GA) * 256 + t;             // 390*256 = 20*78*64 exact
    int l  = tid & 63;
    int t2 = tid >> 6;
    int ks = t2 % NKS;
    int nt = t2 / NKS;
    int n  = nt * 16 + (l & 15);
    int k0 = ks * 32 + ((l >> 4) << 3);
    short v[8];
#pragma unroll
    for (int i = 0; i < 8; ++i) {
      int k = k0 + i;
      float x = 0.f;
      if (n < HID) {
        if (k < DSPAN)                     x = W1[k * HID + n];
      } else if (n >= HP && n < HP + HID) {
        int j = n - HP;
        if (k < DSPAN)                     x = W1[(DSPAN + k) * HID + j];
        else if (k >= 1248 && k < 2468)    x = W1[(1192 + k) * HID + j];
      }
      v[i] = f2bf(x);
    }
    *(bf16x8*)(Wc_fr + (size_t)tid * 8) = *(const bf16x8*)v;
  } else if (b < GA + GB + GC) {              // ---- combined phi table (bf16) ----
    int idx = (b - GA - GB) * 256 + t;
    if (idx < NCMB * HP) {
      int c = idx / HP;
      int j = idx - c * HP;
      float v = 0.f;
      if (j < HID) {
        int si = c % 3;
        int t2 = c / 3;
        int gi = t2 % 7;
        int bi = t2 / 7;
        v = b1[j];
        const float* dp = de + bi * 20;
        const float* gp = ge + gi * 20;
        const float* sp = se + si * 20;
#pragma unroll
        for (int e = 0; e < 20; ++e) {
          v += dp[e] * W1[(3660 + e) * HID + j];
          v += gp[e] * W1[(3680 + e) * HID + j];
          v += sp[e] * W1[(3700 + e) * HID + j];
        }
      }
      combo[idx] = f2bf(v);
    }
  } else {                                    // ---- W2 fragments ----
    int tid = (b - GA - GB - GC) * 256 + t;
    if (tid < 3200) {
      int l  = tid & 63;
      int t2 = tid >> 6;
      int ks = t2 % 5;
      int jt = t2 / 5;
      int n  = jt * 16 + (l & 15);
      int k0 = ks * 32 + ((l >> 4) << 3);
      short v[8];
#pragma unroll
      for (int i = 0; i < 8; ++i) {
        int k = k0 + i;
        float x = (k < HID && n < HID) ? W2[k * HID + n] : 0.f;
        v[i] = f2bf(x);
      }
      *(bf16x8*)(W2_fr + (size_t)tid * 8) = *(const bf16x8*)v;
    }
  }
}

// ---------- batched k-step helper: N loads-in-flight, then N*4 MFMAs ----------
template<int N>
static __device__ __forceinline__ void kbatch(const short*& pa, const short*& pb,
                                              f32x4& a0, f32x4& a1,
                                              f32x4& a2, f32x4& a3) {
  bf16x8 a[N], b0[N], b1[N], b2[N], b3[N];
#pragma unroll
  for (int i = 0; i < N; ++i) {
    a[i]  = *(const bf16x8*)(pa + i * 512);
    b0[i] = *(const bf16x8*)(pb + i * 512);
    b1[i] = *(const bf16x8*)(pb + i * 512 + (size_t)NKS * 512);
    b2[i] = *(const bf16x8*)(pb + i * 512 + (size_t)2 * NKS * 512);
    b3[i] = *(const bf16x8*)(pb + i * 512 + (size_t)3 * NKS * 512);
  }
#pragma unroll
  for (int i = 0; i < N; ++i) {
    a0 = __builtin_amdgcn_mfma_f32_16x16x32_bf16(a[i], b0[i], a0, 0, 0, 0);
    a1 = __builtin_amdgcn_mfma_f32_16x16x32_bf16(a[i], b1[i], a1, 0, 0, 0);
    a2 = __builtin_amdgcn_mfma_f32_16x16x32_bf16(a[i], b2[i], a2, 0, 0, 0);
    a3 = __builtin_amdgcn_mfma_f32_16x16x32_bf16(a[i], b3[i], a3, 0, 0, 0);
  }
  pa += N * 512; pb += N * 512;
}

// ---------- span GEMM: Tpart[z] = A_cat @ Wc (k-chunk z), plain stores ----------
__global__ __launch_bounds__(256)
void span_gemm(const short* __restrict__ A_fr, const short* __restrict__ Wc_fr,
               float* __restrict__ Tpart) {
  int t = threadIdx.x, w = t >> 6, l = t & 63;
  int mt  = blockIdx.y * 4 + w;
  int ntb = blockIdx.x * 4;
  int ksb = blockIdx.z * 13;
  float* Tp = Tpart + (size_t)blockIdx.z * TSZ;
  const short* pa = A_fr + ((size_t)(mt * NKS + ksb) * 64 + l) * 8;
  const short* pb = Wc_fr + ((size_t)(ntb * NKS + ksb) * 64 + l) * 8;
  f32x4 a0 = {0.f, 0.f, 0.f, 0.f}, a1 = a0, a2 = a0, a3 = a0;
  kbatch<5>(pa, pb, a0, a1, a2, a3);   // 13 k-steps as 5/4/4 load batches
  kbatch<4>(pa, pb, a0, a1, a2, a3);
  kbatch<4>(pa, pb, a0, a1, a2, a3);
  int col = l & 15, row4 = (l >> 4) << 2;
  f32x4 acc[4] = {a0, a1, a2, a3};
#pragma unroll
  for (int r = 0; r < 4; ++r) {
    int m = mt * 16 + row4 + r;
    if (m < NSPAN) {
#pragma unroll
      for (int j = 0; j < 4; ++j)
        Tp[m * TW + (ntb + j) * 16 + col] = acc[j][r];
    }
  }
}

// ---------- reduce_T: sum 6 partials -> bf16 Tb ----------
__global__ __launch_bounds__(256)
void reduce_T(const float* __restrict__ Tpart, short* __restrict__ Tb) {
  int i = (blockIdx.x * 256 + threadIdx.x) * 4;   // 625 blocks: 160000 float4 exact
  float4 s = *(const float4*)(Tpart + i);
#pragma unroll
  for (int z = 1; z < KC; ++z) {
    float4 v = *(const float4*)(Tpart + (size_t)z * TSZ + i);
    s.x += v.x; s.y += v.y; s.z += v.z; s.w += v.w;
  }
  bf16x4 r;
  r[0] = f2bf(s.x); r[1] = f2bf(s.y); r[2] = f2bf(s.z); r[3] = f2bf(s.w);
  *(bf16x4*)(Tb + i) = r;
}

// ---------- pair kernel: 128 pairs/block, 32 pairs/wave ----------
// Each wave reuses every W2 B-fragment for two MFMAs (two 16-pair groups):
// 50 B-loads per 100 MFMAs instead of 50 per 50.
__global__ __launch_bounds__(256)
void pair_kernel(const short* __restrict__ Tb, const short* __restrict__ combo,
                 const short* __restrict__ W2_fr,
                 const float* __restrict__ b2, const float* __restrict__ W3,
                 const float* __restrict__ b3, const float* __restrict__ s_m,
                 const int* __restrict__ m_ids, const int* __restrict__ a_ids,
                 const int* __restrict__ dist, const int* __restrict__ genre,
                 const int* __restrict__ spk, float* __restrict__ out) {
  __shared__ short h1s[128 * H1S];            // 43008 B
  __shared__ float w3s[HP], b2s[HP], sm2[128];
  __shared__ int mi[128], ai[128], co[128];

  int t = threadIdx.x;
  int base = blockIdx.x * 128;

  if (t < 128) {
    int p = base + t;
    int m = m_ids[p], a = a_ids[p];
    mi[t] = m; ai[t] = a;
    sm2[t] = s_m[m] + s_m[a];
    int d = dist[p];
    int bb = (d >= 2) + (d >= 3) + (d >= 4) + (d >= 5) + (d >= 8) +
             (d >= 16) + (d >= 32) + (d >= 64);
    co[t] = ((bb * 7 + genre[p]) * 3 + spk[p]) * HP;
  }
  if (t < HP) {
    w3s[t] = (t < HID) ? W3[t] : 0.f;
    b2s[t] = (t < HID) ? b2[t] : 0.f;
  }
  float b3v = b3[0];
  __syncthreads();

  // h1 = relu(Tb_A[m] + Tb_B[a] + combo): 128 pairs x 20 bf16x8 chunks
#pragma unroll
  for (int it = 0; it < 10; ++it) {
    int idx = t + it * 256;
    int p = idx / 20;
    int j = (idx - p * 20) * 8;
    bf16x8 va = *(const bf16x8*)&Tb[mi[p] * TW + j];
    bf16x8 vb = *(const bf16x8*)&Tb[ai[p] * TW + HP + j];
    bf16x8 vc = *(const bf16x8*)&combo[co[p] + j];
    short r[8];
#pragma unroll
    for (int i = 0; i < 8; ++i)
      r[i] = f2bf(fmaxf(bf2f(va[i]) + bf2f(vb[i]) + bf2f(vc[i]), 0.f));
    *(bf16x8*)&h1s[p * H1S + j] = *(const bf16x8*)r;
  }
  __syncthreads();

  int w = t >> 6, l = t & 63;
  int q8 = (l >> 4) << 3;
  const short* hrow0 = h1s + (w * 32 + (l & 15)) * H1S + q8;
  const short* hrow1 = hrow0 + 16 * H1S;
  bf16x8 af0[5], af1[5];
#pragma unroll
  for (int ks = 0; ks < 5; ++ks) {
    af0[ks] = *(const bf16x8*)(hrow0 + ks * 32);
    af1[ks] = *(const bf16x8*)(hrow1 + ks * 32);
  }

  f32x4 acc0[10], acc1[10];
#pragma unroll
  for (int jt = 0; jt < 10; ++jt) {
    acc0[jt] = {0.f, 0.f, 0.f, 0.f};
    acc1[jt] = {0.f, 0.f, 0.f, 0.f};
  }

  const short* pw = W2_fr + l * 8;
#pragma unroll
  for (int jt = 0; jt < 10; ++jt) {
#pragma unroll
    for (int ks = 0; ks < 5; ++ks) {
      bf16x8 bfr = *(const bf16x8*)(pw + (size_t)(jt * 5 + ks) * 512);
      acc0[jt] = __builtin_amdgcn_mfma_f32_16x16x32_bf16(af0[ks], bfr, acc0[jt], 0, 0, 0);
      acc1[jt] = __builtin_amdgcn_mfma_f32_16x16x32_bf16(af1[ks], bfr, acc1[jt], 0, 0, 0);
    }
  }

  // epilogue: relu(h2 + b2) . W3, reduce over the 16 col-lanes
  float part0[4] = {0.f, 0.f, 0.f, 0.f};
  float part1[4] = {0.f, 0.f, 0.f, 0.f};
  int cl = l & 15;
#pragma unroll
  for (int jt = 0; jt < 10; ++jt) {
    int n = jt * 16 + cl;
    float w3v = w3s[n], b2v = b2s[n];
#pragma unroll
    for (int r = 0; r < 4; ++r) {
      part0[r] += fmaxf(acc0[jt][r] + b2v, 0.f) * w3v;
      part1[r] += fmaxf(acc1[jt][r] + b2v, 0.f) * w3v;
    }
  }
#pragma unroll
  for (int off = 8; off >= 1; off >>= 1) {
#pragma unroll
    for (int r = 0; r < 4; ++r) {
      part0[r] += __shfl_xor(part0[r], off, 64);
      part1[r] += __shfl_xor(part1[r], off, 64);
    }
  }
  if (cl == 0) {
    int rowb = (l >> 4) << 2;
#pragma unroll
    for (int r = 0; r < 4; ++r) {
      int pl0 = w * 32 + rowb + r;
      out[base + pl0]      = sm2[pl0]      + part0[r] + b3v;
      out[base + pl0 + 16] = sm2[pl0 + 16] + part1[r] + b3v;
    }
  }
}

extern "C" void kernel_launch(void* const* d_in, const int* in_sizes, int n_in,
                              void* d_out, int out_size, void* d_ws, size_t ws_size,
                              hipStream_t stream) {
  const float* g     = (const float*)d_in[0];
  const float* s_m   = (const float*)d_in[1];
  const int*   m_ids = (const int*)d_in[2];
  const int*   a_ids = (const int*)d_in[3];
  const int*   dist  = (const int*)d_in[4];
  const int*   genre = (const int*)d_in[5];
  const int*   spk   = (const int*)d_in[6];
  const float* de    = (const float*)d_in[7];
  const float* ge    = (const float*)d_in[8];
  const float* se    = (const float*)d_in[9];
  const float* W1    = (const float*)d_in[10];
  const float* b1    = (const float*)d_in[11];
  const float* W2    = (const float*)d_in[12];
  const float* b2    = (const float*)d_in[13];
  const float* W3    = (const float*)d_in[14];
  const float* b3    = (const float*)d_in[15];
  float* out = (float*)d_out;

  float* Tpart = (float*)d_ws;                    // 6 * 640000 f32 = 15.36 MB
  short* Tb    = (short*)(Tpart + (size_t)KC * TSZ); // 640000 bf16 = 1.28 MB
  short* combo = Tb + TSZ;                        // 189*160 bf16
  short* A_fr  = combo + NCMB * HP;               // 128*78*512 bf16 = 10.22 MB
  short* Wc_fr = A_fr + (size_t)NMT * NKS * 512;  // 20*78*512 bf16 = 1.60 MB
  short* W2_fr = Wc_fr + (size_t)NNT * NKS * 512; // 3200*8 bf16

  prep_all<<<GA + GB + GC + GD, 256, 0, stream>>>(
      g, W1, b1, de, ge, se, W2, A_fr, Wc_fr, combo, W2_fr);
  span_gemm<<<dim3(5, 32, KC), 256, 0, stream>>>(A_fr, Wc_fr, Tpart);
  reduce_T<<<625, 256, 0, stream>>>(Tpart, Tb);
  pair_kernel<<<NPAIR / 128, 256, 0, stream>>>(Tb, combo, W2_fr, b2, W3, b3, s_m,
                                               m_ids, a_ids, dist, genre, spk, out);
}

// Round 12
// 123.309 us; speedup vs baseline: 1.0048x; 1.0048x over previous
//
#include <hip/hip_runtime.h>

typedef short bf16x8 __attribute__((ext_vector_type(8)));
typedef short bf16x4 __attribute__((ext_vector_type(4)));
typedef float f32x4  __attribute__((ext_vector_type(4)));

#define NSPAN 2000
#define DSPAN 1220
#define NPAIR 65536
#define HID   150
#define HP    160          // padded hidden width
#define TW    320          // T row: [0,160) A-proj, [160,320) B-proj
#define NKS   78           // total k-steps of 32 (K = 2496 = 2 x 1248)
#define NKH   39           // k-steps per half (g half / g^2 half)
#define NMT   128          // 2048/16 row tiles
#define NNT   20           // 320/16 col tiles
#define KC    6            // k-split chunks [R8-proven]
#define H1S   168          // h1 bf16 row stride (336 B, 16B aligned)
#define NCMB  189          // 9*7*3 phi combos
#define TSZ   (NSPAN * TW) // 640000 elements per T image

// prep_all grid sections
#define GA 1248            // A-fragments
#define GB 390             // Wc-fragments
#define GC 119             // combo phi table (189*160, bf16)
#define GD 13              // W2 fragments (3200)

static __device__ __forceinline__ short f2bf(float x) {
  unsigned u = __builtin_bit_cast(unsigned, x);
  u = (u + 0x7FFFu + ((u >> 16) & 1u)) >> 16;   // RNE
  return (short)u;
}
static __device__ __forceinline__ float bf2f(short s) {
  unsigned u = ((unsigned)(unsigned short)s) << 16;
  return __builtin_bit_cast(float, u);
}

// ---------------- prep_all: fragments + combo table ----------------
__global__ __launch_bounds__(256)
void prep_all(const float* __restrict__ g, const float* __restrict__ W1,
              const float* __restrict__ b1, const float* __restrict__ de,
              const float* __restrict__ ge, const float* __restrict__ se,
              const float* __restrict__ W2, short* __restrict__ A_fr,
              short* __restrict__ Wc_fr, short* __restrict__ combo,
              short* __restrict__ W2_fr) {
  int b = blockIdx.x;
  int t = threadIdx.x;
  if (b < GA) {                               // ---- A fragments ----
    int tid = b * 256 + t;                    // 1248*256 = 128*39*64 exact
    int l  = tid & 63;
    int t2 = tid >> 6;
    int ks = t2 % NKH;
    int mt = t2 / NKH;
    int m  = mt * 16 + (l & 15);
    int k0 = ks * 32 + ((l >> 4) << 3);
    float x[8];
    if (m < NSPAN && k0 + 8 <= DSPAN) {       // g rows 16B-aligned
      float4 f0 = *(const float4*)&g[m * DSPAN + k0];
      float4 f1 = *(const float4*)&g[m * DSPAN + k0 + 4];
      x[0]=f0.x; x[1]=f0.y; x[2]=f0.z; x[3]=f0.w;
      x[4]=f1.x; x[5]=f1.y; x[6]=f1.z; x[7]=f1.w;
    } else {
#pragma unroll
      for (int i = 0; i < 8; ++i) {
        int k = k0 + i;
        x[i] = (m < NSPAN && k < DSPAN) ? g[m * DSPAN + k] : 0.f;
      }
    }
    short v1[8], v2[8];
#pragma unroll
    for (int i = 0; i < 8; ++i) { v1[i] = f2bf(x[i]); v2[i] = f2bf(x[i] * x[i]); }
    size_t o1 = ((size_t)(mt * NKS + ks) * 64 + l) * 8;
    *(bf16x8*)(A_fr + o1) = *(const bf16x8*)v1;
    *(bf16x8*)(A_fr + o1 + (size_t)NKH * 512) = *(const bf16x8*)v2;
  } else if (b < GA + GB) {                   // ---- Wc fragments ----
    int tid = (b - GA) * 256 + t;             // 390*256 = 20*78*64 exact
    int l  = tid & 63;
    int t2 = tid >> 6;
    int ks = t2 % NKS;
    int nt = t2 / NKS;
    int n  = nt * 16 + (l & 15);
    int k0 = ks * 32 + ((l >> 4) << 3);
    short v[8];
#pragma unroll
    for (int i = 0; i < 8; ++i) {
      int k = k0 + i;
      float x = 0.f;
      if (n < HID) {
        if (k < DSPAN)                     x = W1[k * HID + n];
      } else if (n >= HP && n < HP + HID) {
        int j = n - HP;
        if (k < DSPAN)                     x = W1[(DSPAN + k) * HID + j];
        else if (k >= 1248 && k < 2468)    x = W1[(1192 + k) * HID + j];
      }
      v[i] = f2bf(x);
    }
    *(bf16x8*)(Wc_fr + (size_t)tid * 8) = *(const bf16x8*)v;
  } else if (b < GA + GB + GC) {              // ---- combined phi table (bf16) ----
    int idx = (b - GA - GB) * 256 + t;
    if (idx < NCMB * HP) {
      int c = idx / HP;
      int j = idx - c * HP;
      float v = 0.f;
      if (j < HID) {
        int si = c % 3;
        int t2 = c / 3;
        int gi = t2 % 7;
        int bi = t2 / 7;
        v = b1[j];
        const float* dp = de + bi * 20;
        const float* gp = ge + gi * 20;
        const float* sp = se + si * 20;
#pragma unroll
        for (int e = 0; e < 20; ++e) {
          v += dp[e] * W1[(3660 + e) * HID + j];
          v += gp[e] * W1[(3680 + e) * HID + j];
          v += sp[e] * W1[(3700 + e) * HID + j];
        }
      }
      combo[idx] = f2bf(v);
    }
  } else {                                    // ---- W2 fragments ----
    int tid = (b - GA - GB - GC) * 256 + t;
    if (tid < 3200) {
      int l  = tid & 63;
      int t2 = tid >> 6;
      int ks = t2 % 5;
      int jt = t2 / 5;
      int n  = jt * 16 + (l & 15);
      int k0 = ks * 32 + ((l >> 4) << 3);
      short v[8];
#pragma unroll
      for (int i = 0; i < 8; ++i) {
        int k = k0 + i;
        float x = (k < HID && n < HID) ? W2[k * HID + n] : 0.f;
        v[i] = f2bf(x);
      }
      *(bf16x8*)(W2_fr + (size_t)tid * 8) = *(const bf16x8*)v;
    }
  }
}

// ---------- batched k-step helper: N loads-in-flight, then N*4 MFMAs ----------
template<int N>
static __device__ __forceinline__ void kbatch(const short*& pa, const short*& pb,
                                              f32x4& a0, f32x4& a1,
                                              f32x4& a2, f32x4& a3) {
  bf16x8 a[N], b0[N], b1[N], b2[N], b3[N];
#pragma unroll
  for (int i = 0; i < N; ++i) {
    a[i]  = *(const bf16x8*)(pa + i * 512);
    b0[i] = *(const bf16x8*)(pb + i * 512);
    b1[i] = *(const bf16x8*)(pb + i * 512 + (size_t)NKS * 512);
    b2[i] = *(const bf16x8*)(pb + i * 512 + (size_t)2 * NKS * 512);
    b3[i] = *(const bf16x8*)(pb + i * 512 + (size_t)3 * NKS * 512);
  }
#pragma unroll
  for (int i = 0; i < N; ++i) {
    a0 = __builtin_amdgcn_mfma_f32_16x16x32_bf16(a[i], b0[i], a0, 0, 0, 0);
    a1 = __builtin_amdgcn_mfma_f32_16x16x32_bf16(a[i], b1[i], a1, 0, 0, 0);
    a2 = __builtin_amdgcn_mfma_f32_16x16x32_bf16(a[i], b2[i], a2, 0, 0, 0);
    a3 = __builtin_amdgcn_mfma_f32_16x16x32_bf16(a[i], b3[i], a3, 0, 0, 0);
  }
  pa += N * 512; pb += N * 512;
}

// ---------- span GEMM with zero-region K-skip ----------
// Column tiles 0..9 (A-half) have Wc == 0 for kstep >= 39 (g^2 region maps
// only into cols 160..309). Blocks x<2 (tiles 0..7, pure A-half) iterate only
// ksteps 0..38, split over z as 7/7/7/6/6/6. x>=2 keeps the full 78 (13/z).
__global__ __launch_bounds__(256)
void span_gemm(const short* __restrict__ A_fr, const short* __restrict__ Wc_fr,
               float* __restrict__ Tpart) {
  int t = threadIdx.x, w = t >> 6, l = t & 63;
  int mt  = blockIdx.y * 4 + w;
  int x   = blockIdx.x;
  int z   = blockIdx.z;
  int ntb = x * 4;
  int ksb = (x < 2) ? ((z < 3) ? z * 7 : 21 + (z - 3) * 6) : z * 13;
  float* Tp = Tpart + (size_t)z * TSZ;
  const short* pa = A_fr + ((size_t)(mt * NKS + ksb) * 64 + l) * 8;
  const short* pb = Wc_fr + ((size_t)(ntb * NKS + ksb) * 64 + l) * 8;
  f32x4 a0 = {0.f, 0.f, 0.f, 0.f}, a1 = a0, a2 = a0, a3 = a0;
  if (x < 2) {
    if (z < 3) kbatch<7>(pa, pb, a0, a1, a2, a3);
    else       kbatch<6>(pa, pb, a0, a1, a2, a3);
  } else {
    kbatch<5>(pa, pb, a0, a1, a2, a3);   // 13 k-steps as 5/4/4 batches
    kbatch<4>(pa, pb, a0, a1, a2, a3);
    kbatch<4>(pa, pb, a0, a1, a2, a3);
  }
  int col = l & 15, row4 = (l >> 4) << 2;
  f32x4 acc[4] = {a0, a1, a2, a3};
#pragma unroll
  for (int r = 0; r < 4; ++r) {
    int m = mt * 16 + row4 + r;
    if (m < NSPAN) {
#pragma unroll
      for (int j = 0; j < 4; ++j)
        Tp[m * TW + (ntb + j) * 16 + col] = acc[j][r];
    }
  }
}

// ---------- reduce_T: sum 6 partials -> bf16 Tb ----------
__global__ __launch_bounds__(256)
void reduce_T(const float* __restrict__ Tpart, short* __restrict__ Tb) {
  int i = (blockIdx.x * 256 + threadIdx.x) * 4;   // 625 blocks: 160000 float4 exact
  float4 s = *(const float4*)(Tpart + i);
#pragma unroll
  for (int z = 1; z < KC; ++z) {
    float4 v = *(const float4*)(Tpart + (size_t)z * TSZ + i);
    s.x += v.x; s.y += v.y; s.z += v.z; s.w += v.w;
  }
  bf16x4 r;
  r[0] = f2bf(s.x); r[1] = f2bf(s.y); r[2] = f2bf(s.z); r[3] = f2bf(s.w);
  *(bf16x4*)(Tb + i) = r;
}

// ---------- pair kernel: 128 pairs/block, 32 pairs/wave ----------
__global__ __launch_bounds__(256)
void pair_kernel(const short* __restrict__ Tb, const short* __restrict__ combo,
                 const short* __restrict__ W2_fr,
                 const float* __restrict__ b2, const float* __restrict__ W3,
                 const float* __restrict__ b3, const float* __restrict__ s_m,
                 const int* __restrict__ m_ids, const int* __restrict__ a_ids,
                 const int* __restrict__ dist, const int* __restrict__ genre,
                 const int* __restrict__ spk, float* __restrict__ out) {
  __shared__ short h1s[128 * H1S];            // 43008 B
  __shared__ float w3s[HP], b2s[HP], sm2[128];
  __shared__ int mi[128], ai[128], co[128];

  int t = threadIdx.x;
  int base = blockIdx.x * 128;

  if (t < 128) {
    int p = base + t;
    int m = m_ids[p], a = a_ids[p];
    mi[t] = m; ai[t] = a;
    sm2[t] = s_m[m] + s_m[a];
    int d = dist[p];
    int bb = (d >= 2) + (d >= 3) + (d >= 4) + (d >= 5) + (d >= 8) +
             (d >= 16) + (d >= 32) + (d >= 64);
    co[t] = ((bb * 7 + genre[p]) * 3 + spk[p]) * HP;
  }
  if (t < HP) {
    w3s[t] = (t < HID) ? W3[t] : 0.f;
    b2s[t] = (t < HID) ? b2[t] : 0.f;
  }
  float b3v = b3[0];
  __syncthreads();

  // h1 = relu(Tb_A[m] + Tb_B[a] + combo): 128 pairs x 20 bf16x8 chunks
#pragma unroll
  for (int it = 0; it < 10; ++it) {
    int idx = t + it * 256;
    int p = idx / 20;
    int j = (idx - p * 20) * 8;
    bf16x8 va = *(const bf16x8*)&Tb[mi[p] * TW + j];
    bf16x8 vb = *(const bf16x8*)&Tb[ai[p] * TW + HP + j];
    bf16x8 vc = *(const bf16x8*)&combo[co[p] + j];
    short r[8];
#pragma unroll
    for (int i = 0; i < 8; ++i)
      r[i] = f2bf(fmaxf(bf2f(va[i]) + bf2f(vb[i]) + bf2f(vc[i]), 0.f));
    *(bf16x8*)&h1s[p * H1S + j] = *(const bf16x8*)r;
  }
  __syncthreads();

  int w = t >> 6, l = t & 63;
  int q8 = (l >> 4) << 3;
  const short* hrow0 = h1s + (w * 32 + (l & 15)) * H1S + q8;
  const short* hrow1 = hrow0 + 16 * H1S;
  bf16x8 af0[5], af1[5];
#pragma unroll
  for (int ks = 0; ks < 5; ++ks) {
    af0[ks] = *(const bf16x8*)(hrow0 + ks * 32);
    af1[ks] = *(const bf16x8*)(hrow1 + ks * 32);
  }

  f32x4 acc0[10], acc1[10];
#pragma unroll
  for (int jt = 0; jt < 10; ++jt) {
    acc0[jt] = {0.f, 0.f, 0.f, 0.f};
    acc1[jt] = {0.f, 0.f, 0.f, 0.f};
  }

  const short* pw = W2_fr + l * 8;
#pragma unroll
  for (int jt = 0; jt < 10; ++jt) {
#pragma unroll
    for (int ks = 0; ks < 5; ++ks) {
      bf16x8 bfr = *(const bf16x8*)(pw + (size_t)(jt * 5 + ks) * 512);
      acc0[jt] = __builtin_amdgcn_mfma_f32_16x16x32_bf16(af0[ks], bfr, acc0[jt], 0, 0, 0);
      acc1[jt] = __builtin_amdgcn_mfma_f32_16x16x32_bf16(af1[ks], bfr, acc1[jt], 0, 0, 0);
    }
  }

  // epilogue: relu(h2 + b2) . W3, reduce over the 16 col-lanes
  float part0[4] = {0.f, 0.f, 0.f, 0.f};
  float part1[4] = {0.f, 0.f, 0.f, 0.f};
  int cl = l & 15;
#pragma unroll
  for (int jt = 0; jt < 10; ++jt) {
    int n = jt * 16 + cl;
    float w3v = w3s[n], b2v = b2s[n];
#pragma unroll
    for (int r = 0; r < 4; ++r) {
      part0[r] += fmaxf(acc0[jt][r] + b2v, 0.f) * w3v;
      part1[r] += fmaxf(acc1[jt][r] + b2v, 0.f) * w3v;
    }
  }
#pragma unroll
  for (int off = 8; off >= 1; off >>= 1) {
#pragma unroll
    for (int r = 0; r < 4; ++r) {
      part0[r] += __shfl_xor(part0[r], off, 64);
      part1[r] += __shfl_xor(part1[r], off, 64);
    }
  }
  if (cl == 0) {
    int rowb = (l >> 4) << 2;
#pragma unroll
    for (int r = 0; r < 4; ++r) {
      int pl0 = w * 32 + rowb + r;
      out[base + pl0]      = sm2[pl0]      + part0[r] + b3v;
      out[base + pl0 + 16] = sm2[pl0 + 16] + part1[r] + b3v;
    }
  }
}

extern "C" void kernel_launch(void* const* d_in, const int* in_sizes, int n_in,
                              void* d_out, int out_size, void* d_ws, size_t ws_size,
                              hipStream_t stream) {
  const float* g     = (const float*)d_in[0];
  const float* s_m   = (const float*)d_in[1];
  const int*   m_ids = (const int*)d_in[2];
  const int*   a_ids = (const int*)d_in[3];
  const int*   dist  = (const int*)d_in[4];
  const int*   genre = (const int*)d_in[5];
  const int*   spk   = (const int*)d_in[6];
  const float* de    = (const float*)d_in[7];
  const float* ge    = (const float*)d_in[8];
  const float* se    = (const float*)d_in[9];
  const float* W1    = (const float*)d_in[10];
  const float* b1    = (const float*)d_in[11];
  const float* W2    = (const float*)d_in[12];
  const float* b2    = (const float*)d_in[13];
  const float* W3    = (const float*)d_in[14];
  const float* b3    = (const float*)d_in[15];
  float* out = (float*)d_out;

  float* Tpart = (float*)d_ws;                    // 6 * 640000 f32 = 15.36 MB
  short* Tb    = (short*)(Tpart + (size_t)KC * TSZ); // 640000 bf16 = 1.28 MB
  short* combo = Tb + TSZ;                        // 189*160 bf16
  short* A_fr  = combo + NCMB * HP;               // 128*78*512 bf16 = 10.22 MB
  short* Wc_fr = A_fr + (size_t)NMT * NKS * 512;  // 20*78*512 bf16 = 1.60 MB
  short* W2_fr = Wc_fr + (size_t)NNT * NKS * 512; // 3200*8 bf16

  prep_all<<<GA + GB + GC + GD, 256, 0, stream>>>(
      g, W1, b1, de, ge, se, W2, A_fr, Wc_fr, combo, W2_fr);
  span_gemm<<<dim3(5, 32, KC), 256, 0, stream>>>(A_fr, Wc_fr, Tpart);
  reduce_T<<<625, 256, 0, stream>>>(Tpart, Tb);
  pair_kernel<<<NPAIR / 128, 256, 0, stream>>>(Tb, combo, W2_fr, b2, W3, b3, s_m,
                                               m_ids, a_ids, dist, genre, spk, out);
}